// Round 14
// baseline (57.036 us; speedup 1.0000x reference)
//
#include <hip/hip_runtime.h>
#include <cmath>

// 3 graph nodes:
//  N1 prep (512 thr): blocks 0..2R-1:    partb[b,a,p,:] = bf16( sum over half-p of seg(a) )
//                       (SP=2 segment halves -> straggler bytes split across 2 CUs;
//                        within block: col=tid&255, t-parity tid>>8, LDS combine)
//                     blocks 2R..2R+255: Wpb = bf16(W_proj)
//                     block  2R+256:     M'' = tanh(gate) * (W_graph^hops) * diag(1/counts)
//  N2 zmix (512 thr): grid (B, D/16); wave w: c-rows (w&3)*16, K-half (w>>2);
//                     parts-as-K: acc += sum_p partb[b,c,p,khalf] . Wpb[d,khalf]
//                     (B-fragment hoisted: 1 B-load + 2 A-loads + 2 MFMA per k-step)
//                     Y[b,a,:] = sum_c M''[a,c]*(Z0+Z1)[c][dl]
//  N3 out:  out[b,t,:] = x[b,t,:] + Y[b,assign[t],:]   (2048 blocks, nontemporal stores)

typedef __attribute__((ext_vector_type(8))) short bf16x8;
typedef __attribute__((ext_vector_type(4))) float f32x4;

#define SP 2
#define OROWS 8

__device__ inline short f2bf(float f) {            // round-to-nearest-even
    unsigned u = __float_as_uint(f);
    return (short)((u + 0x7FFFu + ((u >> 16) & 1u)) >> 16);
}
__device__ inline int lbound(const int* __restrict__ a, int n, int v) {
    int lo = 0, hi = n;
    while (lo < hi) { int m = (lo + hi) >> 1; if (a[m] < v) lo = m + 1; else hi = m; }
    return lo;
}

// N1 (512 threads per block)
__global__ __launch_bounds__(512) void prep_kernel(
        const float* __restrict__ x, const float* __restrict__ counts,
        const int* __restrict__ assign, const float* __restrict__ Wg,
        const int* __restrict__ hops, const float* __restrict__ Wp,
        const float* __restrict__ gate,
        short* __restrict__ partb, short* __restrict__ Wpb, float* __restrict__ Mp,
        int T, int D, int A, int R) {
    __shared__ float s0[4096];
    __shared__ float s1[4096];
    int bid = blockIdx.x, tid = threadIdx.x;
    int rs = D >> 2;
    int nAB = SP * R;
    if (bid < nAB) {
        int u = bid >> 1, part = bid & 1;
        int b = u / A, a = u - (u / A) * A;
        int* sT = (int*)s1;
        if (tid < 2) sT[tid] = lbound(assign, T, a + tid);
        __syncthreads();
        int t0 = sT[0], t1 = sT[1];
        int len = t1 - t0;
        int p0 = t0 + (len * part) / SP;
        int p1 = t0 + (len * (part + 1)) / SP;
        int col = tid & 255;
        int tp  = tid >> 8;
        const float4* x4 = (const float4*)x + (size_t)b * T * rs;
        float4 acc = make_float4(0.f, 0.f, 0.f, 0.f);
        int t = p0 + tp;
        const float4* p = x4 + (size_t)t * rs + col;
        for (; t + 14 < p1; t += 16) {             // 8 loads, stride 2 rows
            float4 v0 = p[0];
            float4 v1 = p[(size_t)2 * rs];
            float4 v2 = p[(size_t)4 * rs];
            float4 v3 = p[(size_t)6 * rs];
            float4 v4 = p[(size_t)8 * rs];
            float4 v5 = p[(size_t)10 * rs];
            float4 v6 = p[(size_t)12 * rs];
            float4 v7 = p[(size_t)14 * rs];
            acc.x += ((v0.x + v1.x) + (v2.x + v3.x)) + ((v4.x + v5.x) + (v6.x + v7.x));
            acc.y += ((v0.y + v1.y) + (v2.y + v3.y)) + ((v4.y + v5.y) + (v6.y + v7.y));
            acc.z += ((v0.z + v1.z) + (v2.z + v3.z)) + ((v4.z + v5.z) + (v6.z + v7.z));
            acc.w += ((v0.w + v1.w) + (v2.w + v3.w)) + ((v4.w + v5.w) + (v6.w + v7.w));
            p += (size_t)16 * rs;
        }
        for (; t < p1; t += 2) {
            float4 v = *p;
            acc.x += v.x; acc.y += v.y; acc.z += v.z; acc.w += v.w;
            p += (size_t)2 * rs;
        }
        float4* sA = (float4*)s0;
        sA[tid] = acc;
        __syncthreads();
        if (tid < 256) {
            float4 o = sA[tid];
            float4 q = sA[tid + 256];
            o.x += q.x; o.y += q.y; o.z += q.z; o.w += q.w;
            short4 ob;
            ob.x = f2bf(o.x); ob.y = f2bf(o.y); ob.z = f2bf(o.z); ob.w = f2bf(o.w);
            ((short4*)partb)[(size_t)bid * rs + tid] = ob;    // bid = u*SP+part
        }
    } else if (bid < nAB + 256) {
        long long n8 = (long long)D * D / 8;
        for (long long i = (long long)(bid - nAB) * 512 + tid; i < n8; i += 256LL * 512LL) {
            const float4* p = (const float4*)Wp + i * 2;
            float4 v0 = p[0], v1 = p[1];
            short4* q = (short4*)Wpb + i * 2;
            short4 o0, o1;
            o0.x = f2bf(v0.x); o0.y = f2bf(v0.y); o0.z = f2bf(v0.z); o0.w = f2bf(v0.w);
            o1.x = f2bf(v1.x); o1.y = f2bf(v1.y); o1.z = f2bf(v1.z); o1.w = f2bf(v1.w);
            q[0] = o0; q[1] = o1;
        }
    } else {
        int n = A * A;
        for (int i = tid; i < n; i += 512) s0[i] = Wg[i];
        int h = hops[0]; if (h < 1) h = 1;
        for (int it = 1; it < h; ++it) {
            __syncthreads();
            for (int i = tid; i < n; i += 512) {
                int r = i / A, c = i - (i / A) * A;
                float s = 0.f;
                for (int k = 0; k < A; ++k) s += Wg[r * A + k] * s0[k * A + c];
                s1[i] = s;
            }
            __syncthreads();
            for (int i = tid; i < n; i += 512) s0[i] = s1[i];
        }
        __syncthreads();
        float tg = tanhf(gate[0]);
        for (int i = tid; i < n; i += 512) {
            int c = i - (i / A) * A;
            Mp[i] = tg * s0[i] / counts[c];
        }
    }
}

// N2: grid (B, D/16), 512 thr = 8 waves. Wave w: c-rows (w&3)*16..+16, K-half (w>>2).
// parts-as-K: per k-step load 1 B-frag + SP A-frags, SP MFMAs.  Assumes A == 64.
__global__ __launch_bounds__(512) void zmix_kernel(
        const short* __restrict__ partb, const short* __restrict__ Wpb,
        const float* __restrict__ Mp, float* __restrict__ Y, int D, int A) {
    __shared__ float Z_lds[2][64][20];
    int b = blockIdx.x, dblk = blockIdx.y;
    int tid = threadIdx.x;
    int wave = tid >> 6, lane = tid & 63;
    int rc = lane & 15, kq = lane >> 4;
    int half = wave >> 2, w4 = wave & 3;
    int Dh = D >> 1;

    const short* aP0 = partb + ((size_t)(b * A + w4 * 16 + rc) * SP + 0) * D + half * Dh + kq * 8;
    const short* aP1 = aP0 + D;                      // part 1
    const short* bP  = Wpb + (size_t)(dblk * 16 + rc) * D + half * Dh + kq * 8;
    f32x4 acc = {0.f, 0.f, 0.f, 0.f};
    #pragma unroll 8
    for (int k = 0; k < Dh; k += 32) {
        bf16x8 bv = *(const bf16x8*)(bP + k);
        bf16x8 a0 = *(const bf16x8*)(aP0 + k);
        bf16x8 a1 = *(const bf16x8*)(aP1 + k);
        acc = __builtin_amdgcn_mfma_f32_16x16x32_bf16(a0, bv, acc, 0, 0, 0);
        acc = __builtin_amdgcn_mfma_f32_16x16x32_bf16(a1, bv, acc, 0, 0, 0);
    }
    int zr = w4 * 16 + kq * 4;
    #pragma unroll
    for (int j = 0; j < 4; ++j)
        Z_lds[half][zr + j][rc] = acc[j];
    __syncthreads();

    // mix: 512 threads, thread i -> a_ = i>>3, d2 = i&7 (2 floats each)
    int a_ = tid >> 3, d2 = tid & 7;
    const float* Mrow = Mp + (size_t)a_ * A;
    float y0 = 0.f, y1 = 0.f;
    #pragma unroll 8
    for (int c = 0; c < 64; ++c) {
        float w = Mrow[c];
        y0 += w * (Z_lds[0][c][d2 * 2 + 0] + Z_lds[1][c][d2 * 2 + 0]);
        y1 += w * (Z_lds[0][c][d2 * 2 + 1] + Z_lds[1][c][d2 * 2 + 1]);
    }
    float2 yo = make_float2(y0, y1);
    *(float2*)&Y[((size_t)b * A + a_) * D + dblk * 16 + d2 * 2] = yo;
}

// N3: out[b,t,:] = x[b,t,:] + Y[b,assign[t],:]   (B*T/OROWS = 2048 blocks)
__global__ __launch_bounds__(256) void out_kernel(
        const float* __restrict__ x, const float* __restrict__ Y,
        const int* __restrict__ assign, float* __restrict__ out,
        int T, int D, int A) {
    int rs = D >> 2;
    int bt0 = blockIdx.x * OROWS;
    const f32x4* x4 = (const f32x4*)x;
    const f32x4* y4 = (const f32x4*)Y;
    f32x4* o4 = (f32x4*)out;
    #pragma unroll
    for (int r = 0; r < OROWS; ++r) {
        int bt = bt0 + r;
        int b = bt / T;
        int t = bt - b * T;
        int a = assign[t];
        const f32x4* yr = y4 + ((size_t)b * A + a) * rs;
        for (int d4 = threadIdx.x; d4 < rs; d4 += 256) {
            f32x4 xv = x4[(size_t)bt * rs + d4];
            f32x4 yv = yr[d4];
            f32x4 ov = xv + yv;
            __builtin_nontemporal_store(ov, &o4[(size_t)bt * rs + d4]);
        }
    }
}

extern "C" void kernel_launch(void* const* d_in, const int* in_sizes, int n_in,
                              void* d_out, int out_size, void* d_ws, size_t ws_size,
                              hipStream_t stream) {
    const float* x      = (const float*)d_in[0];
    const float* Wp     = (const float*)d_in[1];
    const float* gate   = (const float*)d_in[2];
    const int*   assign = (const int*)d_in[3];
    const float* Wg     = (const float*)d_in[4];
    const float* counts = (const float*)d_in[5];
    const int*   hops   = (const int*)d_in[6];
    float* out = (float*)d_out;

    int T = in_sizes[3];
    int A = in_sizes[5];
    int D = (int)(sqrt((double)in_sizes[1]) + 0.5);
    int B = (int)(in_sizes[0] / ((long long)T * D));
    int R = B * A;

    // workspace: Mp (A*A f32) | Y (R*D f32) | partb (R*SP*D bf16) | Wpb (D*D bf16)
    float* Mp    = (float*)d_ws;
    float* Y     = Mp + (size_t)A * A;
    short* partb = (short*)(Y + (size_t)R * D);
    short* Wpb   = partb + (size_t)R * SP * D;

    prep_kernel<<<SP * R + 257, 512, 0, stream>>>(x, counts, assign, Wg, hops, Wp, gate,
                                                  partb, Wpb, Mp, T, D, A, R);
    dim3 g(B, D / 16);
    zmix_kernel<<<g, 512, 0, stream>>>(partb, Wpb, Mp, Y, D, A);
    out_kernel<<<B * T / OROWS, 256, 0, stream>>>(x, Y, assign, out, T, D, A);
}

// Round 15
// 55.893 us; speedup vs baseline: 1.0205x; 1.0205x over previous
//
#include <hip/hip_runtime.h>
#include <cmath>

// 3 graph nodes (R13 structure, out-kernel tuned):
//  N1 prep (512 thr): blocks 0..R-1:    anchorb[b,a,:] = bf16( sum_{t in seg(a)} x[b,t,:] )
//                     blocks R..R+255:  Wpb = bf16(W_proj)
//                     block  R+256:     M'' = tanh(gate) * (W_graph^hops) * diag(1/counts)
//  N2 zmix (512 thr): grid (B, D/16); waves 0-3: K in [0,D/2), waves 4-7: K in [D/2,D)
//                     Z_half[h][c][dl] via MFMA; Y[b,a,:] = sum_c M''[a,c]*(Z0+Z1)[c][dl]
//  N3 out:  out[b,t,:] = x[b,t,:] + Y[b,assign[t],:]
//           (4096 blocks, nontemporal x loads + nontemporal stores)

typedef __attribute__((ext_vector_type(8))) short bf16x8;
typedef __attribute__((ext_vector_type(4))) float f32x4;

#define OROWS 4

__device__ inline short f2bf(float f) {            // round-to-nearest-even
    unsigned u = __float_as_uint(f);
    return (short)((u + 0x7FFFu + ((u >> 16) & 1u)) >> 16);
}
__device__ inline int lbound(const int* __restrict__ a, int n, int v) {
    int lo = 0, hi = n;
    while (lo < hi) { int m = (lo + hi) >> 1; if (a[m] < v) lo = m + 1; else hi = m; }
    return lo;
}

// N1 (512 threads per block)
__global__ __launch_bounds__(512) void prep_kernel(
        const float* __restrict__ x, const float* __restrict__ counts,
        const int* __restrict__ assign, const float* __restrict__ Wg,
        const int* __restrict__ hops, const float* __restrict__ Wp,
        const float* __restrict__ gate,
        short* __restrict__ anchorb, short* __restrict__ Wpb, float* __restrict__ Mp,
        int T, int D, int A, int R) {
    __shared__ float s0[4096];
    __shared__ float s1[4096];
    int bid = blockIdx.x, tid = threadIdx.x;
    int rs = D >> 2;
    if (bid < R) {
        int b = bid / A, a = bid - (bid / A) * A;
        int* sT = (int*)s1;
        if (tid < 2) sT[tid] = lbound(assign, T, a + tid);
        __syncthreads();
        int t0 = sT[0], t1 = sT[1];
        int col = tid & 255;
        int tp  = tid >> 8;
        const float4* x4 = (const float4*)x + (size_t)b * T * rs;
        float4 acc = make_float4(0.f, 0.f, 0.f, 0.f);
        int t = t0 + tp;
        const float4* p = x4 + (size_t)t * rs + col;
        for (; t + 14 < t1; t += 16) {
            float4 v0 = p[0];
            float4 v1 = p[(size_t)2 * rs];
            float4 v2 = p[(size_t)4 * rs];
            float4 v3 = p[(size_t)6 * rs];
            float4 v4 = p[(size_t)8 * rs];
            float4 v5 = p[(size_t)10 * rs];
            float4 v6 = p[(size_t)12 * rs];
            float4 v7 = p[(size_t)14 * rs];
            acc.x += ((v0.x + v1.x) + (v2.x + v3.x)) + ((v4.x + v5.x) + (v6.x + v7.x));
            acc.y += ((v0.y + v1.y) + (v2.y + v3.y)) + ((v4.y + v5.y) + (v6.y + v7.y));
            acc.z += ((v0.z + v1.z) + (v2.z + v3.z)) + ((v4.z + v5.z) + (v6.z + v7.z));
            acc.w += ((v0.w + v1.w) + (v2.w + v3.w)) + ((v4.w + v5.w) + (v6.w + v7.w));
            p += (size_t)16 * rs;
        }
        for (; t < t1; t += 2) {
            float4 v = *p;
            acc.x += v.x; acc.y += v.y; acc.z += v.z; acc.w += v.w;
            p += (size_t)2 * rs;
        }
        float4* sA = (float4*)s0;
        sA[tid] = acc;
        __syncthreads();
        if (tid < 256) {
            float4 o = sA[tid];
            float4 q = sA[tid + 256];
            o.x += q.x; o.y += q.y; o.z += q.z; o.w += q.w;
            short4 ob;
            ob.x = f2bf(o.x); ob.y = f2bf(o.y); ob.z = f2bf(o.z); ob.w = f2bf(o.w);
            ((short4*)anchorb)[(size_t)bid * rs + tid] = ob;
        }
    } else if (bid < R + 256) {
        long long n8 = (long long)D * D / 8;
        for (long long i = (long long)(bid - R) * 512 + tid; i < n8; i += 256LL * 512LL) {
            const float4* p = (const float4*)Wp + i * 2;
            float4 v0 = p[0], v1 = p[1];
            short4* q = (short4*)Wpb + i * 2;
            short4 o0, o1;
            o0.x = f2bf(v0.x); o0.y = f2bf(v0.y); o0.z = f2bf(v0.z); o0.w = f2bf(v0.w);
            o1.x = f2bf(v1.x); o1.y = f2bf(v1.y); o1.z = f2bf(v1.z); o1.w = f2bf(v1.w);
            q[0] = o0; q[1] = o1;
        }
    } else {
        int n = A * A;
        for (int i = tid; i < n; i += 512) s0[i] = Wg[i];
        int h = hops[0]; if (h < 1) h = 1;
        for (int it = 1; it < h; ++it) {
            __syncthreads();
            for (int i = tid; i < n; i += 512) {
                int r = i / A, c = i - (i / A) * A;
                float s = 0.f;
                for (int k = 0; k < A; ++k) s += Wg[r * A + k] * s0[k * A + c];
                s1[i] = s;
            }
            __syncthreads();
            for (int i = tid; i < n; i += 512) s0[i] = s1[i];
        }
        __syncthreads();
        float tg = tanhf(gate[0]);
        for (int i = tid; i < n; i += 512) {
            int c = i - (i / A) * A;
            Mp[i] = tg * s0[i] / counts[c];
        }
    }
}

// N2: grid (B, D/16), 512 thr = 8 waves. Wave w: c-rows (w&3)*16..+16, K-half (w>>2).
// A/B-frag: lane holds row (lane&15), k = khalf*D/2 + (lane>>4)*8 + j.
// D: c = (lane>>4)*4+reg, d = lane&15.   Assumes A == 64.
__global__ __launch_bounds__(512) void zmix_kernel(
        const short* __restrict__ anchorb, const short* __restrict__ Wpb,
        const float* __restrict__ Mp, float* __restrict__ Y, int D, int A) {
    __shared__ float Z_lds[2][64][20];
    int b = blockIdx.x, dblk = blockIdx.y;
    int tid = threadIdx.x;
    int wave = tid >> 6, lane = tid & 63;
    int rc = lane & 15, kq = lane >> 4;
    int half = wave >> 2, w4 = wave & 3;
    int Dh = D >> 1;

    const short* aP = anchorb + (size_t)(b * A + w4 * 16 + rc) * D + half * Dh + kq * 8;
    const short* bP = Wpb + (size_t)(dblk * 16 + rc) * D + half * Dh + kq * 8;
    f32x4 acc = {0.f, 0.f, 0.f, 0.f};
    #pragma unroll 8
    for (int k = 0; k < Dh; k += 32) {
        bf16x8 av = *(const bf16x8*)(aP + k);
        bf16x8 bv = *(const bf16x8*)(bP + k);
        acc = __builtin_amdgcn_mfma_f32_16x16x32_bf16(av, bv, acc, 0, 0, 0);
    }
    int zr = w4 * 16 + kq * 4;
    #pragma unroll
    for (int j = 0; j < 4; ++j)
        Z_lds[half][zr + j][rc] = acc[j];
    __syncthreads();

    // mix: 512 threads, thread i -> a_ = i>>3, d2 = i&7 (2 floats each)
    int a_ = tid >> 3, d2 = tid & 7;
    const float* Mrow = Mp + (size_t)a_ * A;
    float y0 = 0.f, y1 = 0.f;
    #pragma unroll 8
    for (int c = 0; c < 64; ++c) {
        float w = Mrow[c];
        y0 += w * (Z_lds[0][c][d2 * 2 + 0] + Z_lds[1][c][d2 * 2 + 0]);
        y1 += w * (Z_lds[0][c][d2 * 2 + 1] + Z_lds[1][c][d2 * 2 + 1]);
    }
    float2 yo = make_float2(y0, y1);
    *(float2*)&Y[((size_t)b * A + a_) * D + dblk * 16 + d2 * 2] = yo;
}

// N3: out[b,t,:] = x[b,t,:] + Y[b,assign[t],:]   (B*T/OROWS = 4096 blocks)
__global__ __launch_bounds__(256) void out_kernel(
        const float* __restrict__ x, const float* __restrict__ Y,
        const int* __restrict__ assign, float* __restrict__ out,
        int T, int D, int A) {
    int rs = D >> 2;
    int bt0 = blockIdx.x * OROWS;
    const f32x4* x4 = (const f32x4*)x;
    const f32x4* y4 = (const f32x4*)Y;
    f32x4* o4 = (f32x4*)out;
    #pragma unroll
    for (int r = 0; r < OROWS; ++r) {
        int bt = bt0 + r;
        int b = bt / T;
        int t = bt - b * T;
        int a = assign[t];
        const f32x4* yr = y4 + ((size_t)b * A + a) * rs;
        for (int d4 = threadIdx.x; d4 < rs; d4 += 256) {
            f32x4 xv = __builtin_nontemporal_load(&x4[(size_t)bt * rs + d4]);
            f32x4 yv = yr[d4];
            f32x4 ov = xv + yv;
            __builtin_nontemporal_store(ov, &o4[(size_t)bt * rs + d4]);
        }
    }
}

extern "C" void kernel_launch(void* const* d_in, const int* in_sizes, int n_in,
                              void* d_out, int out_size, void* d_ws, size_t ws_size,
                              hipStream_t stream) {
    const float* x      = (const float*)d_in[0];
    const float* Wp     = (const float*)d_in[1];
    const float* gate   = (const float*)d_in[2];
    const int*   assign = (const int*)d_in[3];
    const float* Wg     = (const float*)d_in[4];
    const float* counts = (const float*)d_in[5];
    const int*   hops   = (const int*)d_in[6];
    float* out = (float*)d_out;

    int T = in_sizes[3];
    int A = in_sizes[5];
    int D = (int)(sqrt((double)in_sizes[1]) + 0.5);
    int B = (int)(in_sizes[0] / ((long long)T * D));
    int R = B * A;

    // workspace: Mp (A*A f32) | Y (R*D f32) | anchorb (R*D bf16) | Wpb (D*D bf16)
    float* Mp      = (float*)d_ws;
    float* Y       = Mp + (size_t)A * A;
    short* anchorb = (short*)(Y + (size_t)R * D);
    short* Wpb     = anchorb + (size_t)R * D;

    prep_kernel<<<R + 257, 512, 0, stream>>>(x, counts, assign, Wg, hops, Wp, gate,
                                             anchorb, Wpb, Mp, T, D, A, R);
    dim3 g(B, D / 16);
    zmix_kernel<<<g, 512, 0, stream>>>(anchorb, Wpb, Mp, Y, D, A);
    out_kernel<<<B * T / OROWS, 256, 0, stream>>>(x, Y, assign, out, T, D, A);
}

// Round 16
// 52.094 us; speedup vs baseline: 1.0949x; 1.0729x over previous
//
#include <hip/hip_runtime.h>
#include <cmath>

// 3 graph nodes (R13 configuration — best verified: 52.39 us):
//  N1 prep (512 thr): blocks 0..R-1:    anchorb[b,a,:] = bf16( sum_{t in seg(a)} x[b,t,:] )
//                     blocks R..R+255:  Wpb = bf16(W_proj)
//                     block  R+256:     M'' = tanh(gate) * (W_graph^hops) * diag(1/counts)
//  N2 zmix (512 thr): grid (B, D/16); waves 0-3: K in [0,D/2), waves 4-7: K in [D/2,D)
//                     Z_half[h][c][dl] via MFMA; Y[b,a,:] = sum_c M''[a,c]*(Z0+Z1)[c][dl]
//  N3 out:  out[b,t,:] = x[b,t,:] + Y[b,assign[t],:]
//           (2048 blocks, plain x loads [L3-resident], nontemporal stores)

typedef __attribute__((ext_vector_type(8))) short bf16x8;
typedef __attribute__((ext_vector_type(4))) float f32x4;

#define OROWS 8

__device__ inline short f2bf(float f) {            // round-to-nearest-even
    unsigned u = __float_as_uint(f);
    return (short)((u + 0x7FFFu + ((u >> 16) & 1u)) >> 16);
}
__device__ inline int lbound(const int* __restrict__ a, int n, int v) {
    int lo = 0, hi = n;
    while (lo < hi) { int m = (lo + hi) >> 1; if (a[m] < v) lo = m + 1; else hi = m; }
    return lo;
}

// N1 (512 threads per block)
__global__ __launch_bounds__(512) void prep_kernel(
        const float* __restrict__ x, const float* __restrict__ counts,
        const int* __restrict__ assign, const float* __restrict__ Wg,
        const int* __restrict__ hops, const float* __restrict__ Wp,
        const float* __restrict__ gate,
        short* __restrict__ anchorb, short* __restrict__ Wpb, float* __restrict__ Mp,
        int T, int D, int A, int R) {
    __shared__ float s0[4096];
    __shared__ float s1[4096];
    int bid = blockIdx.x, tid = threadIdx.x;
    int rs = D >> 2;
    if (bid < R) {
        int b = bid / A, a = bid - (bid / A) * A;
        int* sT = (int*)s1;
        if (tid < 2) sT[tid] = lbound(assign, T, a + tid);
        __syncthreads();
        int t0 = sT[0], t1 = sT[1];
        int col = tid & 255;
        int tp  = tid >> 8;
        const float4* x4 = (const float4*)x + (size_t)b * T * rs;
        float4 acc = make_float4(0.f, 0.f, 0.f, 0.f);
        int t = t0 + tp;
        const float4* p = x4 + (size_t)t * rs + col;
        for (; t + 14 < t1; t += 16) {
            float4 v0 = p[0];
            float4 v1 = p[(size_t)2 * rs];
            float4 v2 = p[(size_t)4 * rs];
            float4 v3 = p[(size_t)6 * rs];
            float4 v4 = p[(size_t)8 * rs];
            float4 v5 = p[(size_t)10 * rs];
            float4 v6 = p[(size_t)12 * rs];
            float4 v7 = p[(size_t)14 * rs];
            acc.x += ((v0.x + v1.x) + (v2.x + v3.x)) + ((v4.x + v5.x) + (v6.x + v7.x));
            acc.y += ((v0.y + v1.y) + (v2.y + v3.y)) + ((v4.y + v5.y) + (v6.y + v7.y));
            acc.z += ((v0.z + v1.z) + (v2.z + v3.z)) + ((v4.z + v5.z) + (v6.z + v7.z));
            acc.w += ((v0.w + v1.w) + (v2.w + v3.w)) + ((v4.w + v5.w) + (v6.w + v7.w));
            p += (size_t)16 * rs;
        }
        for (; t < t1; t += 2) {
            float4 v = *p;
            acc.x += v.x; acc.y += v.y; acc.z += v.z; acc.w += v.w;
            p += (size_t)2 * rs;
        }
        float4* sA = (float4*)s0;
        sA[tid] = acc;
        __syncthreads();
        if (tid < 256) {
            float4 o = sA[tid];
            float4 q = sA[tid + 256];
            o.x += q.x; o.y += q.y; o.z += q.z; o.w += q.w;
            short4 ob;
            ob.x = f2bf(o.x); ob.y = f2bf(o.y); ob.z = f2bf(o.z); ob.w = f2bf(o.w);
            ((short4*)anchorb)[(size_t)bid * rs + tid] = ob;
        }
    } else if (bid < R + 256) {
        long long n8 = (long long)D * D / 8;
        for (long long i = (long long)(bid - R) * 512 + tid; i < n8; i += 256LL * 512LL) {
            const float4* p = (const float4*)Wp + i * 2;
            float4 v0 = p[0], v1 = p[1];
            short4* q = (short4*)Wpb + i * 2;
            short4 o0, o1;
            o0.x = f2bf(v0.x); o0.y = f2bf(v0.y); o0.z = f2bf(v0.z); o0.w = f2bf(v0.w);
            o1.x = f2bf(v1.x); o1.y = f2bf(v1.y); o1.z = f2bf(v1.z); o1.w = f2bf(v1.w);
            q[0] = o0; q[1] = o1;
        }
    } else {
        int n = A * A;
        for (int i = tid; i < n; i += 512) s0[i] = Wg[i];
        int h = hops[0]; if (h < 1) h = 1;
        for (int it = 1; it < h; ++it) {
            __syncthreads();
            for (int i = tid; i < n; i += 512) {
                int r = i / A, c = i - (i / A) * A;
                float s = 0.f;
                for (int k = 0; k < A; ++k) s += Wg[r * A + k] * s0[k * A + c];
                s1[i] = s;
            }
            __syncthreads();
            for (int i = tid; i < n; i += 512) s0[i] = s1[i];
        }
        __syncthreads();
        float tg = tanhf(gate[0]);
        for (int i = tid; i < n; i += 512) {
            int c = i - (i / A) * A;
            Mp[i] = tg * s0[i] / counts[c];
        }
    }
}

// N2: grid (B, D/16), 512 thr = 8 waves. Wave w: c-rows (w&3)*16..+16, K-half (w>>2).
// A/B-frag: lane holds row (lane&15), k = khalf*D/2 + (lane>>4)*8 + j.
// D: c = (lane>>4)*4+reg, d = lane&15.   Assumes A == 64.
__global__ __launch_bounds__(512) void zmix_kernel(
        const short* __restrict__ anchorb, const short* __restrict__ Wpb,
        const float* __restrict__ Mp, float* __restrict__ Y, int D, int A) {
    __shared__ float Z_lds[2][64][20];
    int b = blockIdx.x, dblk = blockIdx.y;
    int tid = threadIdx.x;
    int wave = tid >> 6, lane = tid & 63;
    int rc = lane & 15, kq = lane >> 4;
    int half = wave >> 2, w4 = wave & 3;
    int Dh = D >> 1;

    const short* aP = anchorb + (size_t)(b * A + w4 * 16 + rc) * D + half * Dh + kq * 8;
    const short* bP = Wpb + (size_t)(dblk * 16 + rc) * D + half * Dh + kq * 8;
    f32x4 acc = {0.f, 0.f, 0.f, 0.f};
    #pragma unroll 8
    for (int k = 0; k < Dh; k += 32) {
        bf16x8 av = *(const bf16x8*)(aP + k);
        bf16x8 bv = *(const bf16x8*)(bP + k);
        acc = __builtin_amdgcn_mfma_f32_16x16x32_bf16(av, bv, acc, 0, 0, 0);
    }
    int zr = w4 * 16 + kq * 4;
    #pragma unroll
    for (int j = 0; j < 4; ++j)
        Z_lds[half][zr + j][rc] = acc[j];
    __syncthreads();

    // mix: 512 threads, thread i -> a_ = i>>3, d2 = i&7 (2 floats each)
    int a_ = tid >> 3, d2 = tid & 7;
    const float* Mrow = Mp + (size_t)a_ * A;
    float y0 = 0.f, y1 = 0.f;
    #pragma unroll 8
    for (int c = 0; c < 64; ++c) {
        float w = Mrow[c];
        y0 += w * (Z_lds[0][c][d2 * 2 + 0] + Z_lds[1][c][d2 * 2 + 0]);
        y1 += w * (Z_lds[0][c][d2 * 2 + 1] + Z_lds[1][c][d2 * 2 + 1]);
    }
    float2 yo = make_float2(y0, y1);
    *(float2*)&Y[((size_t)b * A + a_) * D + dblk * 16 + d2 * 2] = yo;
}

// N3: out[b,t,:] = x[b,t,:] + Y[b,assign[t],:]   (B*T/OROWS = 2048 blocks)
__global__ __launch_bounds__(256) void out_kernel(
        const float* __restrict__ x, const float* __restrict__ Y,
        const int* __restrict__ assign, float* __restrict__ out,
        int T, int D, int A) {
    int rs = D >> 2;
    int bt0 = blockIdx.x * OROWS;
    const f32x4* x4 = (const f32x4*)x;
    const f32x4* y4 = (const f32x4*)Y;
    f32x4* o4 = (f32x4*)out;
    #pragma unroll
    for (int r = 0; r < OROWS; ++r) {
        int bt = bt0 + r;
        int b = bt / T;
        int t = bt - b * T;
        int a = assign[t];
        const f32x4* yr = y4 + ((size_t)b * A + a) * rs;
        for (int d4 = threadIdx.x; d4 < rs; d4 += 256) {
            f32x4 xv = x4[(size_t)bt * rs + d4];
            f32x4 yv = yr[d4];
            f32x4 ov = xv + yv;
            __builtin_nontemporal_store(ov, &o4[(size_t)bt * rs + d4]);
        }
    }
}

extern "C" void kernel_launch(void* const* d_in, const int* in_sizes, int n_in,
                              void* d_out, int out_size, void* d_ws, size_t ws_size,
                              hipStream_t stream) {
    const float* x      = (const float*)d_in[0];
    const float* Wp     = (const float*)d_in[1];
    const float* gate   = (const float*)d_in[2];
    const int*   assign = (const int*)d_in[3];
    const float* Wg     = (const float*)d_in[4];
    const float* counts = (const float*)d_in[5];
    const int*   hops   = (const int*)d_in[6];
    float* out = (float*)d_out;

    int T = in_sizes[3];
    int A = in_sizes[5];
    int D = (int)(sqrt((double)in_sizes[1]) + 0.5);
    int B = (int)(in_sizes[0] / ((long long)T * D));
    int R = B * A;

    // workspace: Mp (A*A f32) | Y (R*D f32) | anchorb (R*D bf16) | Wpb (D*D bf16)
    float* Mp      = (float*)d_ws;
    float* Y       = Mp + (size_t)A * A;
    short* anchorb = (short*)(Y + (size_t)R * D);
    short* Wpb     = anchorb + (size_t)R * D;

    prep_kernel<<<R + 257, 512, 0, stream>>>(x, counts, assign, Wg, hops, Wp, gate,
                                             anchorb, Wpb, Mp, T, D, A, R);
    dim3 g(B, D / 16);
    zmix_kernel<<<g, 512, 0, stream>>>(anchorb, Wpb, Mp, Y, D, A);
    out_kernel<<<B * T / OROWS, 256, 0, stream>>>(x, Y, assign, out, T, D, A);
}